// Round 2
// 280.177 us; speedup vs baseline: 1.0193x; 1.0193x over previous
//
#include <hip/hip_runtime.h>
#include <hip/hip_bf16.h>
#include <math.h>

#define DIM 1024
#define HID 2048
#define NE  4
#define NT  4096            // B*T tokens
#define KW  (NE*HID)        // 8192, GEMM2 K / Hw leading dim
#define KSPLIT 2
#define KCH (KW / KSPLIT)   // 4096 per split

typedef __attribute__((ext_vector_type(8))) short short8;
typedef __attribute__((ext_vector_type(4))) short short4v;
typedef __attribute__((ext_vector_type(4))) float floatx4;

// ---- helpers ----------------------------------------------------------------

__device__ __forceinline__ void async_cp16(const void* g, void* l) {
  __builtin_amdgcn_global_load_lds(
      (const __attribute__((address_space(1))) void*)g,
      (__attribute__((address_space(3))) void*)l, 16, 0, 0);
}

__device__ __forceinline__ short f2bf(float f) {
  union { float f; unsigned u; } x; x.f = f;
  unsigned r = x.u + 0x7fffu + ((x.u >> 16) & 1u);   // round-to-nearest-even
  return (short)(r >> 16);
}

// fast GELU (tanh form via sigmoid + v_exp/v_rcp); |err| ~2e-4 vs exact
__device__ __forceinline__ float gelu_fast(float v) {
  float u = 1.595769122f * (v + 0.044715f * v * v * v);
  return v * __builtin_amdgcn_rcpf(1.0f + __expf(-u));
}

// counted-vmcnt wait + barrier as SEPARATE statements (m201-proven pattern):
// never drains the load queue to 0 in the main loop (T4).
#define WBAR(N) do { \
    asm volatile("s_waitcnt vmcnt(" #N ")" ::: "memory"); \
    __builtin_amdgcn_s_barrier(); \
  } while (0)

// ---- router + x->bf16: weights = softmax(x@Wr+br); xb = bf16(x) -------------
__global__ void router_cvt(const float* __restrict__ x, const float* __restrict__ Wr,
                           const float* __restrict__ br, float* __restrict__ wgt,
                           short* __restrict__ xb) {
  const int wv = threadIdx.x >> 6, lane = threadIdx.x & 63;
  const int t = blockIdx.x * 4 + wv;
  const float* xr = x + (size_t)t * DIM;
  short* xo = xb + (size_t)t * DIM;
  float a0 = 0.f, a1 = 0.f, a2 = 0.f, a3 = 0.f;
  #pragma unroll
  for (int p = 0; p < 4; p++) {
    const int d = p * 256 + lane * 4;
    floatx4 v = *(const floatx4*)&xr[d];
    short4v o;
    #pragma unroll
    for (int j = 0; j < 4; j++) {
      o[j] = f2bf(v[j]);
      floatx4 wr = *(const floatx4*)&Wr[(d + j) * 4];
      a0 += v[j] * wr[0]; a1 += v[j] * wr[1];
      a2 += v[j] * wr[2]; a3 += v[j] * wr[3];
    }
    *(short4v*)&xo[d] = o;
  }
  #pragma unroll
  for (int off = 32; off; off >>= 1) {
    a0 += __shfl_down(a0, off);
    a1 += __shfl_down(a1, off);
    a2 += __shfl_down(a2, off);
    a3 += __shfl_down(a3, off);
  }
  a0 = __shfl(a0, 0); a1 = __shfl(a1, 0); a2 = __shfl(a2, 0); a3 = __shfl(a3, 0);
  float s0 = a0 + br[0], s1 = a1 + br[1], s2 = a2 + br[2], s3 = a3 + br[3];
  float m = fmaxf(fmaxf(s0, s1), fmaxf(s2, s3));
  float e0 = __expf(s0 - m), e1 = __expf(s1 - m), e2 = __expf(s2 - m), e3 = __expf(s3 - m);
  float inv = 1.f / (e0 + e1 + e2 + e3);
  float v = (lane == 0) ? e0 : (lane == 1) ? e1 : (lane == 2) ? e2 : e3;
  if (lane < 4) wgt[t * 4 + lane] = v * inv;
}

// ---- merged weight transpose: W1 [E][DIM][HID]->[E][HID][DIM],
//      W2 [KW][DIM]->[DIM][KW]; fp32 in, bf16 out.
#define TP_PADR 136   // LDS row stride (shorts); 272B, 16B-aligned
__global__ void transpose_all(const float* __restrict__ W1, short* __restrict__ w1t,
                              const float* __restrict__ W2, short* __restrict__ w2t) {
  __shared__ __align__(16) short tile[32 * TP_PADR];
  const int b = blockIdx.x;
  const float* in; short* out; int R, C, xt, yt;
  if (b < 2048) {                 // W1: per expert R=DIM rows, C=HID cols
    const int e = b >> 9, rem = b & 511;
    xt = rem & 63; yt = rem >> 6; R = DIM; C = HID;
    in = W1 + (size_t)e * DIM * HID; out = w1t + (size_t)e * DIM * HID;
  } else {                        // W2: R=KW rows, C=DIM cols
    const int rem = b - 2048;
    xt = rem & 31; yt = rem >> 5; R = KW; C = DIM;
    in = W2; out = w2t;
  }
  const int c0 = xt * 32, r0 = yt * 128;
  const int t = threadIdx.x;
  const int cin = (t & 7) * 4;
  const int rin = t >> 3;                 // 0..31
  #pragma unroll
  for (int i = 0; i < 4; i++) {
    const int r = rin + i * 32;
    floatx4 v = *(const floatx4*)&in[(size_t)(r0 + r) * C + c0 + cin];
    #pragma unroll
    for (int j = 0; j < 4; j++)
      tile[(cin + j) * TP_PADR + r] = f2bf(v[j]);
  }
  __syncthreads();
  const int ct = t >> 3;                  // 0..31
  #pragma unroll
  for (int i = 0; i < 2; i++) {
    const int rc = (t & 7) + 8 * i;       // 8-short chunks
    short8 vv = *(const short8*)&tile[ct * TP_PADR + rc * 8];
    *(short8*)&out[(size_t)(c0 + ct) * R + r0 + rc * 8] = vv;
  }
}

// ============================================================================
// GEMMs: 256-wide tiles, 8 waves (512 thr), BK=32, ring-4 LDS pipeline.
//   - prefetch depth 2, ONE "s_waitcnt vmcnt(N); s_barrier" per K-step
//     (N=8/6 steady; tail 4/3 then 0) -> loads stay in flight across barriers.
//   - setprio(1) around the MFMA cluster (T5).
//   - LDS layout: two m-rows packed per 128B row; 16B chunk cc of row r holds
//     (m = 2r + (u>>2), kc = u&3) with u = cc ^ (r&7).  Read side:
//     cswz = (quad | ((lrow&1)<<2)) ^ (lrow>>1); within each 16-lane phase
//     group every 16B bank-group is hit by exactly 2 lanes (free, m136).
//   - ring hazard: stage(t+2) targets slot (t+2)&3; concurrent readers are in
//     iters t-1 / t (slots (t-1)&3, t&3) -> disjoint since 4 does not divide 2,3.
//     vmcnt ledger (gemm1, 4 loads/stage): 12 outstanding -> WBAR(8) retires
//     exactly the oldest slot; barrier then publishes it to all waves.
// XCD-aware 1-D grid decode as before (bid&7 = XCD).
// ============================================================================

// ---- GEMM1: Hw[t][e*HID+h] = bf16( w[t][e] * gelu(x @ W1[e] + b1[e]) ) ------
// grid: 512 blocks. tiles 256x256: 16 m x 32 n. per XCD: 4 m x 16 n.
__global__ __launch_bounds__(512, 2)
void gemm1_kernel(const short* __restrict__ xb, const short* __restrict__ w1t,
                  const float* __restrict__ b1, const float* __restrict__ wgt,
                  short* __restrict__ hw) {
  __shared__ __align__(16) short lds[65536];   // A: 4 slots x 8192, B at +32768
  const int b = blockIdx.x;
  const int xcd = b & 7, slot = b >> 3;        // slot 0..63
  const int m0 = ((xcd & 3) * 4 + (slot & 3)) * 256;
  const int n0 = ((xcd >> 2) * 16 + (slot >> 2)) * 256;
  const int tid = threadIdx.x;
  const int lane = tid & 63, wv = tid >> 6;
  const int wm = (wv >> 2) * 128, wn = (wv & 3) * 64;   // per-wave 128x64
  const int quad = lane >> 4, lrow = lane & 15;

  // staging source mapping (pre-swizzled global address, linear LDS dest)
  const int srow = tid >> 3, su = (tid & 7) ^ (srow & 7);
  const int sm = 2 * srow + (su >> 2), skc = su & 3;
  const short* srcA0 = xb + (size_t)(m0 + sm) * DIM + skc * 8;
  const short* srcA1 = srcA0 + (size_t)128 * DIM;
  const short* srcB0 = w1t + (size_t)(n0 + sm) * DIM + skc * 8;
  const short* srcB1 = srcB0 + (size_t)128 * DIM;

  // fragment read offsets (shorts, loop-invariant)
  const int cswz = (quad | ((lrow & 1) << 2)) ^ (lrow >> 1);
  const int offA = ((wm >> 1) + (lrow >> 1)) * 64 + cswz * 8;
  const int offB = ((wn >> 1) + (lrow >> 1)) * 64 + cswz * 8;

  floatx4 acc[8][4];
  #pragma unroll
  for (int i = 0; i < 8; i++)
    #pragma unroll
    for (int j = 0; j < 4; j++) acc[i][j] = (floatx4)0.f;

#define G1_STAGE(sl, tk) do { \
    short* Ab = &lds[(sl) * 8192]; short* Bb = &lds[32768 + (sl) * 8192]; \
    async_cp16(srcA0 + (tk) * 32, Ab + tid * 8); \
    async_cp16(srcA1 + (tk) * 32, Ab + 4096 + tid * 8); \
    async_cp16(srcB0 + (tk) * 32, Bb + tid * 8); \
    async_cp16(srcB1 + (tk) * 32, Bb + 4096 + tid * 8); \
  } while (0)

#define G1_COMP(sl) do { \
    const short* Ab = &lds[(sl) * 8192]; const short* Bb = &lds[32768 + (sl) * 8192]; \
    short8 af[8], bfr[4]; \
    _Pragma("unroll") for (int i = 0; i < 8; i++) \
      af[i] = *(const short8*)&Ab[offA + i * 512]; \
    _Pragma("unroll") for (int j = 0; j < 4; j++) \
      bfr[j] = *(const short8*)&Bb[offB + j * 512]; \
    __builtin_amdgcn_s_setprio(1); \
    _Pragma("unroll") for (int i = 0; i < 8; i++) \
      _Pragma("unroll") for (int j = 0; j < 4; j++) \
        acc[i][j] = __builtin_amdgcn_mfma_f32_16x16x32_bf16(af[i], bfr[j], acc[i][j], 0, 0, 0); \
    __builtin_amdgcn_s_setprio(0); \
  } while (0)

  G1_STAGE(0, 0);
  G1_STAGE(1, 1);
  for (int t = 0; t < 28; t += 4) {            // K-steps 0..27, stages 2..29
    G1_STAGE(2, t + 2); WBAR(8); G1_COMP(0);
    G1_STAGE(3, t + 3); WBAR(8); G1_COMP(1);
    G1_STAGE(0, t + 4); WBAR(8); G1_COMP(2);
    G1_STAGE(1, t + 5); WBAR(8); G1_COMP(3);
  }
  G1_STAGE(2, 30); WBAR(8); G1_COMP(0);        // K-step 28
  G1_STAGE(3, 31); WBAR(8); G1_COMP(1);        // K-step 29
  WBAR(4); G1_COMP(2);                          // K-step 30
  WBAR(0); G1_COMP(3);                          // K-step 31
#undef G1_STAGE
#undef G1_COMP

  // epilogue: bias + fast gelu + router-weight fold + bf16 store
  const int e = n0 >> 11;                       // 256-col tile within one expert
  #pragma unroll
  for (int i = 0; i < 8; i++) {
    const int rbase = m0 + wm + i * 16 + quad * 4;
    float w4[4];
    #pragma unroll
    for (int r = 0; r < 4; r++) w4[r] = wgt[(rbase + r) * NE + e];
    #pragma unroll
    for (int j = 0; j < 4; j++) {
      const int col = n0 + wn + j * 16 + lrow;  // global n = e*HID + h
      const float b1v = b1[e * HID + (col & (HID - 1))];
      #pragma unroll
      for (int r = 0; r < 4; r++) {
        float v = acc[i][j][r] + b1v;
        hw[(size_t)(rbase + r) * KW + col] = f2bf(w4[r] * gelu_fast(v));
      }
    }
  }
}

// ---- GEMM2 (split-K=2): out[t][d] = Hw @ W2t^T + sum_e w[t][e]*b2[e][d] -----
// grid: 256 blocks. tiles 256x128: 16 m x 8 n x 2 kz. per XCD: 4 m x 8 n, 1 kz.
__global__ __launch_bounds__(512, 2)
void gemm2_kernel(const short* __restrict__ hw, const short* __restrict__ w2t,
                  const float* __restrict__ b2, const float* __restrict__ wgt,
                  float* __restrict__ out, float* __restrict__ part) {
  __shared__ __align__(16) short lds[49152];   // A: 4 x 8192, B: 4 x 4096 at +32768
  const int b = blockIdx.x;
  const int xcd = b & 7, slot = b >> 3;        // slot 0..31
  const int kz = xcd >> 2;
  const int m0 = ((xcd & 3) * 4 + (slot & 3)) * 256;
  const int n0 = (slot >> 2) * 128;
  const int tid = threadIdx.x;
  const int lane = tid & 63, wv = tid >> 6;
  const int wm = (wv >> 1) * 64, wn = (wv & 1) * 64;   // per-wave 64x64
  const int quad = lane >> 4, lrow = lane & 15;

  const int srow = tid >> 3, su = (tid & 7) ^ (srow & 7);
  const int sm = 2 * srow + (su >> 2), skc = su & 3;
  const short* srcA0 = hw + (size_t)(m0 + sm) * KW + kz * KCH + skc * 8;
  const short* srcA1 = srcA0 + (size_t)128 * KW;
  const short* srcB0 = w2t + (size_t)(n0 + sm) * KW + kz * KCH + skc * 8;

  const int cswz = (quad | ((lrow & 1) << 2)) ^ (lrow >> 1);
  const int offA = ((wm >> 1) + (lrow >> 1)) * 64 + cswz * 8;
  const int offB = ((wn >> 1) + (lrow >> 1)) * 64 + cswz * 8;

  floatx4 acc[4][4];
  #pragma unroll
  for (int i = 0; i < 4; i++)
    #pragma unroll
    for (int j = 0; j < 4; j++) acc[i][j] = (floatx4)0.f;

#define G2_STAGE(sl, tk) do { \
    short* Ab = &lds[(sl) * 8192]; short* Bb = &lds[32768 + (sl) * 4096]; \
    async_cp16(srcA0 + (tk) * 32, Ab + tid * 8); \
    async_cp16(srcA1 + (tk) * 32, Ab + 4096 + tid * 8); \
    async_cp16(srcB0 + (tk) * 32, Bb + tid * 8); \
  } while (0)

#define G2_COMP(sl) do { \
    const short* Ab = &lds[(sl) * 8192]; const short* Bb = &lds[32768 + (sl) * 4096]; \
    short8 af[4], bfr[4]; \
    _Pragma("unroll") for (int i = 0; i < 4; i++) \
      af[i] = *(const short8*)&Ab[offA + i * 512]; \
    _Pragma("unroll") for (int j = 0; j < 4; j++) \
      bfr[j] = *(const short8*)&Bb[offB + j * 512]; \
    __builtin_amdgcn_s_setprio(1); \
    _Pragma("unroll") for (int i = 0; i < 4; i++) \
      _Pragma("unroll") for (int j = 0; j < 4; j++) \
        acc[i][j] = __builtin_amdgcn_mfma_f32_16x16x32_bf16(af[i], bfr[j], acc[i][j], 0, 0, 0); \
    __builtin_amdgcn_s_setprio(0); \
  } while (0)

  G2_STAGE(0, 0);
  G2_STAGE(1, 1);
  for (int t = 0; t < 124; t += 4) {           // K-steps 0..123, stages 2..125
    G2_STAGE(2, t + 2); WBAR(6); G2_COMP(0);
    G2_STAGE(3, t + 3); WBAR(6); G2_COMP(1);
    G2_STAGE(0, t + 4); WBAR(6); G2_COMP(2);
    G2_STAGE(1, t + 5); WBAR(6); G2_COMP(3);
  }
  G2_STAGE(2, 126); WBAR(6); G2_COMP(0);       // K-step 124
  G2_STAGE(3, 127); WBAR(6); G2_COMP(1);       // K-step 125
  WBAR(3); G2_COMP(2);                          // K-step 126
  WBAR(0); G2_COMP(3);                          // K-step 127
#undef G2_STAGE
#undef G2_COMP

  if (kz == 0) {
    #pragma unroll
    for (int i = 0; i < 4; i++) {
      const int rbase = m0 + wm + i * 16 + quad * 4;
      floatx4 wr[4];
      #pragma unroll
      for (int r = 0; r < 4; r++) wr[r] = *(const floatx4*)&wgt[(rbase + r) * NE];
      #pragma unroll
      for (int j = 0; j < 4; j++) {
        const int col = n0 + wn + j * 16 + lrow;
        float b2v[4];
        #pragma unroll
        for (int eI = 0; eI < 4; eI++) b2v[eI] = b2[eI * DIM + col];
        #pragma unroll
        for (int r = 0; r < 4; r++) {
          float bias = wr[r][0] * b2v[0] + wr[r][1] * b2v[1] +
                       wr[r][2] * b2v[2] + wr[r][3] * b2v[3];
          out[(size_t)(rbase + r) * DIM + col] = acc[i][j][r] + bias;
        }
      }
    }
  } else {
    #pragma unroll
    for (int i = 0; i < 4; i++) {
      const int rbase = m0 + wm + i * 16 + quad * 4;
      #pragma unroll
      for (int j = 0; j < 4; j++) {
        const int col = n0 + wn + j * 16 + lrow;
        #pragma unroll
        for (int r = 0; r < 4; r++)
          part[(size_t)(rbase + r) * DIM + col] = acc[i][j][r];
      }
    }
  }
}

// ---- reduce: out += part ----------------------------------------------------
__global__ void reduce_out(float* __restrict__ out, const float* __restrict__ part) {
  int i = (blockIdx.x * 256 + threadIdx.x) * 4;
  floatx4 v = *(const floatx4*)&out[i];
  floatx4 a = *(const floatx4*)&part[i];
  v = v + a;
  *(floatx4*)&out[i] = v;
}

// ---- launch -----------------------------------------------------------------

extern "C" void kernel_launch(void* const* d_in, const int* in_sizes, int n_in,
                              void* d_out, int out_size, void* d_ws, size_t ws_size,
                              hipStream_t stream) {
  const float* x  = (const float*)d_in[0];
  const float* W1 = (const float*)d_in[1];
  const float* b1 = (const float*)d_in[2];
  const float* W2 = (const float*)d_in[3];
  const float* b2 = (const float*)d_in[4];
  const float* Wr = (const float*)d_in[5];
  const float* br = (const float*)d_in[6];
  float* out = (float*)d_out;

  // layout (bytes):
  //   wgt  @ 0        64 KB   fp32 [NT][NE]
  //   w2t  @ 64K      16 MB   bf16 [DIM][KW]
  //   hw   @ ~16.1M   64 MB   bf16 [NT][KW]
  //   xb   @ ~80.1M    8 MB   bf16 [NT][DIM]     (dead after gemm1)
  //   w1t  @ ~88.5M   16 MB   bf16 [NE][HID][DIM](dead after gemm1)
  //   part @ ~80.1M   16 MB   fp32 [NT][DIM]     (aliases xb+w1t head)
  char* ws = (char*)d_ws;
  float* wgt = (float*)(ws);
  short* w2t = (short*)(ws + 65536);
  short* hw  = (short*)(ws + 65536 + 16777216);
  short* xb  = (short*)(ws + 65536 + 16777216 + 67108864);
  short* w1t = (short*)(ws + 65536 + 16777216 + 67108864 + 8388608);
  float* part= (float*)(ws + 65536 + 16777216 + 67108864);   // aliases xb/w1t

  hipLaunchKernelGGL(router_cvt, dim3(NT / 4), dim3(256), 0, stream, x, Wr, br, wgt, xb);
  hipLaunchKernelGGL(transpose_all, dim3(2048 + 2048), dim3(256), 0, stream,
                     W1, w1t, W2, w2t);
  hipLaunchKernelGGL(gemm1_kernel, dim3(512), dim3(512), 0, stream,
                     xb, w1t, b1, wgt, hw);
  hipLaunchKernelGGL(gemm2_kernel, dim3(256), dim3(512), 0, stream,
                     hw, w2t, b2, wgt, out, part);
  hipLaunchKernelGGL(reduce_out, dim3(NT * DIM / 1024), dim3(256), 0, stream, out, part);
}

// Round 3
// 278.874 us; speedup vs baseline: 1.0240x; 1.0047x over previous
//
#include <hip/hip_runtime.h>
#include <hip/hip_bf16.h>
#include <math.h>

#define DIM 1024
#define HID 2048
#define NE  4
#define NT  4096            // B*T tokens
#define KW  (NE*HID)        // 8192, GEMM2 K / Hw leading dim
#define KSPLIT 2
#define KCH (KW / KSPLIT)   // 4096 per split

typedef __attribute__((ext_vector_type(8))) short short8;
typedef __attribute__((ext_vector_type(4))) short short4v;
typedef __attribute__((ext_vector_type(4))) float floatx4;

// ---- helpers ----------------------------------------------------------------

__device__ __forceinline__ void async_cp16(const void* g, void* l) {
  __builtin_amdgcn_global_load_lds(
      (const __attribute__((address_space(1))) void*)g,
      (__attribute__((address_space(3))) void*)l, 16, 0, 0);
}

__device__ __forceinline__ short f2bf(float f) {
  union { float f; unsigned u; } x; x.f = f;
  unsigned r = x.u + 0x7fffu + ((x.u >> 16) & 1u);   // round-to-nearest-even
  return (short)(r >> 16);
}

// fast GELU (tanh form via sigmoid + v_exp/v_rcp); |err| ~2e-4 vs exact
__device__ __forceinline__ float gelu_fast(float v) {
  float u = 1.595769122f * (v + 0.044715f * v * v * v);
  return v * __builtin_amdgcn_rcpf(1.0f + __expf(-u));
}

#define VMW(n) asm volatile("s_waitcnt vmcnt(" #n ")" ::: "memory")
#define BAR()  __builtin_amdgcn_s_barrier()

// ---- router + x->bf16: weights = softmax(x@Wr+br); xb = bf16(x) -------------
__global__ void router_cvt(const float* __restrict__ x, const float* __restrict__ Wr,
                           const float* __restrict__ br, float* __restrict__ wgt,
                           short* __restrict__ xb) {
  const int wv = threadIdx.x >> 6, lane = threadIdx.x & 63;
  const int t = blockIdx.x * 4 + wv;
  const float* xr = x + (size_t)t * DIM;
  short* xo = xb + (size_t)t * DIM;
  float a0 = 0.f, a1 = 0.f, a2 = 0.f, a3 = 0.f;
  #pragma unroll
  for (int p = 0; p < 4; p++) {
    const int d = p * 256 + lane * 4;
    floatx4 v = *(const floatx4*)&xr[d];
    short4v o;
    #pragma unroll
    for (int j = 0; j < 4; j++) {
      o[j] = f2bf(v[j]);
      floatx4 wr = *(const floatx4*)&Wr[(d + j) * 4];
      a0 += v[j] * wr[0]; a1 += v[j] * wr[1];
      a2 += v[j] * wr[2]; a3 += v[j] * wr[3];
    }
    *(short4v*)&xo[d] = o;
  }
  #pragma unroll
  for (int off = 32; off; off >>= 1) {
    a0 += __shfl_down(a0, off);
    a1 += __shfl_down(a1, off);
    a2 += __shfl_down(a2, off);
    a3 += __shfl_down(a3, off);
  }
  a0 = __shfl(a0, 0); a1 = __shfl(a1, 0); a2 = __shfl(a2, 0); a3 = __shfl(a3, 0);
  float s0 = a0 + br[0], s1 = a1 + br[1], s2 = a2 + br[2], s3 = a3 + br[3];
  float m = fmaxf(fmaxf(s0, s1), fmaxf(s2, s3));
  float e0 = __expf(s0 - m), e1 = __expf(s1 - m), e2 = __expf(s2 - m), e3 = __expf(s3 - m);
  float inv = 1.f / (e0 + e1 + e2 + e3);
  float v = (lane == 0) ? e0 : (lane == 1) ? e1 : (lane == 2) ? e2 : e3;
  if (lane < 4) wgt[t * 4 + lane] = v * inv;
}

// ---- merged weight transpose: W1 [E][DIM][HID]->[E][HID][DIM],
//      W2 [KW][DIM]->[DIM][KW]; fp32 in, bf16 out.
#define TP_PADR 136   // LDS row stride (shorts); 272B, 16B-aligned
__global__ void transpose_all(const float* __restrict__ W1, short* __restrict__ w1t,
                              const float* __restrict__ W2, short* __restrict__ w2t) {
  __shared__ __align__(16) short tile[32 * TP_PADR];
  const int b = blockIdx.x;
  const float* in; short* out; int R, C, xt, yt;
  if (b < 2048) {                 // W1: per expert R=DIM rows, C=HID cols
    const int e = b >> 9, rem = b & 511;
    xt = rem & 63; yt = rem >> 6; R = DIM; C = HID;
    in = W1 + (size_t)e * DIM * HID; out = w1t + (size_t)e * DIM * HID;
  } else {                        // W2: R=KW rows, C=DIM cols
    const int rem = b - 2048;
    xt = rem & 31; yt = rem >> 5; R = KW; C = DIM;
    in = W2; out = w2t;
  }
  const int c0 = xt * 32, r0 = yt * 128;
  const int t = threadIdx.x;
  const int cin = (t & 7) * 4;
  const int rin = t >> 3;                 // 0..31
  #pragma unroll
  for (int i = 0; i < 4; i++) {
    const int r = rin + i * 32;
    floatx4 v = *(const floatx4*)&in[(size_t)(r0 + r) * C + c0 + cin];
    #pragma unroll
    for (int j = 0; j < 4; j++)
      tile[(cin + j) * TP_PADR + r] = f2bf(v[j]);
  }
  __syncthreads();
  const int ct = t >> 3;                  // 0..31
  #pragma unroll
  for (int i = 0; i < 2; i++) {
    const int rc = (t & 7) + 8 * i;       // 8-short chunks
    short8 vv = *(const short8*)&tile[ct * TP_PADR + rc * 8];
    *(short8*)&out[(size_t)(c0 + ct) * R + r0 + rc * 8] = vv;
  }
}

// ============================================================================
// GEMMs: 256-wide tiles, 8 waves (512 thr), BK=32, ring-4 LDS, fine 2-phase
// interleave per K-step (m196/m201: the per-phase ds_read∥stage∥MFMA
// interleave is the lever, not the vmcnt alone):
//   ph0: stage A(t+2); vmcnt(steady); barrier; read B + A-lo; 16 MFMA
//   ph1: stage B(t+2);                         read A-hi;     16 MFMA
// ph1 needs no barrier: its reads (slot t) were certified at ph0's barrier
// (A(t) staged 4 phases earlier; every wave's vmcnt retired its own share).
// Ring distance under skew<=2 phases: writes target slots (t+2)&3,(t+3)&3;
// readers hold t&3,(t+1)&3 -> disjoint. Ledger (gemm1 2+2 loads/step):
// steady vmcnt(6) retires exactly A(t),B(t); tail 4->0. gemm2 (2+1): 5, 3->0.
// setprio(1) around each MFMA cluster. XCD-aware 1-D grid decode (bid&7=XCD).
// ============================================================================

// ---- GEMM1: Hw[t][e*HID+h] = bf16( w[t][e] * gelu(x @ W1[e] + b1[e]) ) ------
// grid: 512 blocks. tiles 256x256: 16 m x 32 n. per XCD: 4 m x 16 n.
__global__ __launch_bounds__(512, 2)
void gemm1_kernel(const short* __restrict__ xb, const short* __restrict__ w1t,
                  const float* __restrict__ b1, const float* __restrict__ wgt,
                  short* __restrict__ hw) {
  __shared__ __align__(16) short lds[65536];   // A: 4 slots x 8192, B at +32768
  const int b = blockIdx.x;
  const int xcd = b & 7, slot = b >> 3;        // slot 0..63
  const int m0 = ((xcd & 3) * 4 + (slot & 3)) * 256;
  const int n0 = ((xcd >> 2) * 16 + (slot >> 2)) * 256;
  const int tid = threadIdx.x;
  const int lane = tid & 63, wv = tid >> 6;
  const int wm = (wv >> 2) * 128, wn = (wv & 3) * 64;   // per-wave 128x64
  const int quad = lane >> 4, lrow = lane & 15;

  // staging source mapping (pre-swizzled global address, linear LDS dest)
  const int srow = tid >> 3, su = (tid & 7) ^ (srow & 7);
  const int sm = 2 * srow + (su >> 2), skc = su & 3;
  const short* srcA0 = xb + (size_t)(m0 + sm) * DIM + skc * 8;
  const short* srcA1 = srcA0 + (size_t)128 * DIM;
  const short* srcB0 = w1t + (size_t)(n0 + sm) * DIM + skc * 8;
  const short* srcB1 = srcB0 + (size_t)128 * DIM;

  // fragment read offsets (shorts, loop-invariant)
  const int cswz = (quad | ((lrow & 1) << 2)) ^ (lrow >> 1);
  const int offA = ((wm >> 1) + (lrow >> 1)) * 64 + cswz * 8;
  const int offB = ((wn >> 1) + (lrow >> 1)) * 64 + cswz * 8;

  floatx4 acc[8][4];
  #pragma unroll
  for (int i = 0; i < 8; i++)
    #pragma unroll
    for (int j = 0; j < 4; j++) acc[i][j] = (floatx4)0.f;

  short8 af[4], bfr[4];

#define G1_SA(sl, tk) do { short* Ab = &lds[(sl) * 8192]; \
    async_cp16(srcA0 + (tk) * 32, Ab + tid * 8); \
    async_cp16(srcA1 + (tk) * 32, Ab + 4096 + tid * 8); } while (0)
#define G1_SB(sl, tk) do { short* Bb = &lds[32768 + (sl) * 8192]; \
    async_cp16(srcB0 + (tk) * 32, Bb + tid * 8); \
    async_cp16(srcB1 + (tk) * 32, Bb + 4096 + tid * 8); } while (0)

#define G1_PH0(sl) do { \
    const short* Ab = &lds[(sl) * 8192]; const short* Bb = &lds[32768 + (sl) * 8192]; \
    _Pragma("unroll") for (int j = 0; j < 4; j++) \
      bfr[j] = *(const short8*)&Bb[offB + j * 512]; \
    _Pragma("unroll") for (int i = 0; i < 4; i++) \
      af[i] = *(const short8*)&Ab[offA + i * 512]; \
    __builtin_amdgcn_s_setprio(1); \
    _Pragma("unroll") for (int i = 0; i < 4; i++) \
      _Pragma("unroll") for (int j = 0; j < 4; j++) \
        acc[i][j] = __builtin_amdgcn_mfma_f32_16x16x32_bf16(af[i], bfr[j], acc[i][j], 0, 0, 0); \
    __builtin_amdgcn_s_setprio(0); } while (0)
#define G1_PH1(sl) do { \
    const short* Ab = &lds[(sl) * 8192]; \
    _Pragma("unroll") for (int i = 0; i < 4; i++) \
      af[i] = *(const short8*)&Ab[offA + (4 + i) * 512]; \
    __builtin_amdgcn_s_setprio(1); \
    _Pragma("unroll") for (int i = 0; i < 4; i++) \
      _Pragma("unroll") for (int j = 0; j < 4; j++) \
        acc[4 + i][j] = __builtin_amdgcn_mfma_f32_16x16x32_bf16(af[i], bfr[j], acc[4 + i][j], 0, 0, 0); \
    __builtin_amdgcn_s_setprio(0); } while (0)

  // prologue: tiles 0,1 fully staged (8 loads in flight)
  G1_SA(0, 0); G1_SB(0, 0); G1_SA(1, 1); G1_SB(1, 1);
  // steady tiles 0..27 (stage t+2)
  for (int t = 0; t < 28; t += 4) {
    G1_SA(2, t + 2); VMW(6); BAR(); G1_PH0(0); G1_SB(2, t + 2); G1_PH1(0);
    G1_SA(3, t + 3); VMW(6); BAR(); G1_PH0(1); G1_SB(3, t + 3); G1_PH1(1);
    G1_SA(0, t + 4); VMW(6); BAR(); G1_PH0(2); G1_SB(0, t + 4); G1_PH1(2);
    G1_SA(1, t + 5); VMW(6); BAR(); G1_PH0(3); G1_SB(1, t + 5); G1_PH1(3);
  }
  // tiles 28,29 steady (stage 30,31)
  G1_SA(2, 30); VMW(6); BAR(); G1_PH0(0); G1_SB(2, 30); G1_PH1(0);
  G1_SA(3, 31); VMW(6); BAR(); G1_PH0(1); G1_SB(3, 31); G1_PH1(1);
  // tile 30: in-flight A30,B30,A31,B31 -> retire A30,B30
  VMW(4); BAR(); G1_PH0(2); G1_PH1(2);
  // tile 31: drain
  VMW(0); BAR(); G1_PH0(3); G1_PH1(3);
#undef G1_SA
#undef G1_SB
#undef G1_PH0
#undef G1_PH1

  // epilogue: bias + fast gelu + router-weight fold + bf16 store
  const int e = n0 >> 11;                       // 256-col tile within one expert
  #pragma unroll
  for (int i = 0; i < 8; i++) {
    const int rbase = m0 + wm + i * 16 + quad * 4;
    float w4[4];
    #pragma unroll
    for (int r = 0; r < 4; r++) w4[r] = wgt[(rbase + r) * NE + e];
    #pragma unroll
    for (int j = 0; j < 4; j++) {
      const int col = n0 + wn + j * 16 + lrow;  // global n = e*HID + h
      const float b1v = b1[e * HID + (col & (HID - 1))];
      #pragma unroll
      for (int r = 0; r < 4; r++) {
        float v = acc[i][j][r] + b1v;
        hw[(size_t)(rbase + r) * KW + col] = f2bf(w4[r] * gelu_fast(v));
      }
    }
  }
}

// ---- GEMM2 (split-K=2): out[t][d] = Hw @ W2t^T + sum_e w[t][e]*b2[e][d] -----
// grid: 256 blocks. tiles 256x128: 16 m x 8 n x 2 kz. per XCD: 4 m x 8 n, 1 kz.
__global__ __launch_bounds__(512, 2)
void gemm2_kernel(const short* __restrict__ hw, const short* __restrict__ w2t,
                  const float* __restrict__ b2, const float* __restrict__ wgt,
                  float* __restrict__ out, float* __restrict__ part) {
  __shared__ __align__(16) short lds[49152];   // A: 4 x 8192, B: 4 x 4096 at +32768
  const int b = blockIdx.x;
  const int xcd = b & 7, slot = b >> 3;        // slot 0..31
  const int kz = xcd >> 2;
  const int m0 = ((xcd & 3) * 4 + (slot & 3)) * 256;
  const int n0 = (slot >> 2) * 128;
  const int tid = threadIdx.x;
  const int lane = tid & 63, wv = tid >> 6;
  const int wm = (wv >> 1) * 64, wn = (wv & 1) * 64;   // per-wave 64x64
  const int quad = lane >> 4, lrow = lane & 15;

  const int srow = tid >> 3, su = (tid & 7) ^ (srow & 7);
  const int sm = 2 * srow + (su >> 2), skc = su & 3;
  const short* srcA0 = hw + (size_t)(m0 + sm) * KW + kz * KCH + skc * 8;
  const short* srcA1 = srcA0 + (size_t)128 * KW;
  const short* srcB0 = w2t + (size_t)(n0 + sm) * KW + kz * KCH + skc * 8;

  const int cswz = (quad | ((lrow & 1) << 2)) ^ (lrow >> 1);
  const int offA = ((wm >> 1) + (lrow >> 1)) * 64 + cswz * 8;
  const int offB = ((wn >> 1) + (lrow >> 1)) * 64 + cswz * 8;

  floatx4 acc[4][4];
  #pragma unroll
  for (int i = 0; i < 4; i++)
    #pragma unroll
    for (int j = 0; j < 4; j++) acc[i][j] = (floatx4)0.f;

  short8 af[2], bfr[4];

#define G2_SA(sl, tk) do { short* Ab = &lds[(sl) * 8192]; \
    async_cp16(srcA0 + (tk) * 32, Ab + tid * 8); \
    async_cp16(srcA1 + (tk) * 32, Ab + 4096 + tid * 8); } while (0)
#define G2_SB(sl, tk) do { short* Bb = &lds[32768 + (sl) * 4096]; \
    async_cp16(srcB0 + (tk) * 32, Bb + tid * 8); } while (0)

#define G2_PH0(sl) do { \
    const short* Ab = &lds[(sl) * 8192]; const short* Bb = &lds[32768 + (sl) * 4096]; \
    _Pragma("unroll") for (int j = 0; j < 4; j++) \
      bfr[j] = *(const short8*)&Bb[offB + j * 512]; \
    _Pragma("unroll") for (int i = 0; i < 2; i++) \
      af[i] = *(const short8*)&Ab[offA + i * 512]; \
    __builtin_amdgcn_s_setprio(1); \
    _Pragma("unroll") for (int i = 0; i < 2; i++) \
      _Pragma("unroll") for (int j = 0; j < 4; j++) \
        acc[i][j] = __builtin_amdgcn_mfma_f32_16x16x32_bf16(af[i], bfr[j], acc[i][j], 0, 0, 0); \
    __builtin_amdgcn_s_setprio(0); } while (0)
#define G2_PH1(sl) do { \
    const short* Ab = &lds[(sl) * 8192]; \
    _Pragma("unroll") for (int i = 0; i < 2; i++) \
      af[i] = *(const short8*)&Ab[offA + (2 + i) * 512]; \
    __builtin_amdgcn_s_setprio(1); \
    _Pragma("unroll") for (int i = 0; i < 2; i++) \
      _Pragma("unroll") for (int j = 0; j < 4; j++) \
        acc[2 + i][j] = __builtin_amdgcn_mfma_f32_16x16x32_bf16(af[i], bfr[j], acc[2 + i][j], 0, 0, 0); \
    __builtin_amdgcn_s_setprio(0); } while (0)

  // prologue: tiles 0,1 staged (6 loads in flight)
  G2_SA(0, 0); G2_SB(0, 0); G2_SA(1, 1); G2_SB(1, 1);
  // steady tiles 0..123 (stage t+2)
  for (int t = 0; t < 124; t += 4) {
    G2_SA(2, t + 2); VMW(5); BAR(); G2_PH0(0); G2_SB(2, t + 2); G2_PH1(0);
    G2_SA(3, t + 3); VMW(5); BAR(); G2_PH0(1); G2_SB(3, t + 3); G2_PH1(1);
    G2_SA(0, t + 4); VMW(5); BAR(); G2_PH0(2); G2_SB(0, t + 4); G2_PH1(2);
    G2_SA(1, t + 5); VMW(5); BAR(); G2_PH0(3); G2_SB(1, t + 5); G2_PH1(3);
  }
  // tiles 124,125 steady (stage 126,127)
  G2_SA(2, 126); VMW(5); BAR(); G2_PH0(0); G2_SB(2, 126); G2_PH1(0);
  G2_SA(3, 127); VMW(5); BAR(); G2_PH0(1); G2_SB(3, 127); G2_PH1(1);
  // tile 126: in-flight A126,B126,A127,B127 -> retire A126,B126
  VMW(3); BAR(); G2_PH0(2); G2_PH1(2);
  // tile 127: drain
  VMW(0); BAR(); G2_PH0(3); G2_PH1(3);
#undef G2_SA
#undef G2_SB
#undef G2_PH0
#undef G2_PH1

  if (kz == 0) {
    #pragma unroll
    for (int i = 0; i < 4; i++) {
      const int rbase = m0 + wm + i * 16 + quad * 4;
      floatx4 wr[4];
      #pragma unroll
      for (int r = 0; r < 4; r++) wr[r] = *(const floatx4*)&wgt[(rbase + r) * NE];
      #pragma unroll
      for (int j = 0; j < 4; j++) {
        const int col = n0 + wn + j * 16 + lrow;
        float b2v[4];
        #pragma unroll
        for (int eI = 0; eI < 4; eI++) b2v[eI] = b2[eI * DIM + col];
        #pragma unroll
        for (int r = 0; r < 4; r++) {
          float bias = wr[r][0] * b2v[0] + wr[r][1] * b2v[1] +
                       wr[r][2] * b2v[2] + wr[r][3] * b2v[3];
          out[(size_t)(rbase + r) * DIM + col] = acc[i][j][r] + bias;
        }
      }
    }
  } else {
    #pragma unroll
    for (int i = 0; i < 4; i++) {
      const int rbase = m0 + wm + i * 16 + quad * 4;
      #pragma unroll
      for (int j = 0; j < 4; j++) {
        const int col = n0 + wn + j * 16 + lrow;
        #pragma unroll
        for (int r = 0; r < 4; r++)
          part[(size_t)(rbase + r) * DIM + col] = acc[i][j][r];
      }
    }
  }
}

// ---- reduce: out += part ----------------------------------------------------
__global__ void reduce_out(float* __restrict__ out, const float* __restrict__ part) {
  int i = (blockIdx.x * 256 + threadIdx.x) * 4;
  floatx4 v = *(const floatx4*)&out[i];
  floatx4 a = *(const floatx4*)&part[i];
  v = v + a;
  *(floatx4*)&out[i] = v;
}

// ---- launch -----------------------------------------------------------------

extern "C" void kernel_launch(void* const* d_in, const int* in_sizes, int n_in,
                              void* d_out, int out_size, void* d_ws, size_t ws_size,
                              hipStream_t stream) {
  const float* x  = (const float*)d_in[0];
  const float* W1 = (const float*)d_in[1];
  const float* b1 = (const float*)d_in[2];
  const float* W2 = (const float*)d_in[3];
  const float* b2 = (const float*)d_in[4];
  const float* Wr = (const float*)d_in[5];
  const float* br = (const float*)d_in[6];
  float* out = (float*)d_out;

  // layout (bytes):
  //   wgt  @ 0        64 KB   fp32 [NT][NE]
  //   w2t  @ 64K      16 MB   bf16 [DIM][KW]
  //   hw   @ ~16.1M   64 MB   bf16 [NT][KW]
  //   xb   @ ~80.1M    8 MB   bf16 [NT][DIM]     (dead after gemm1)
  //   w1t  @ ~88.5M   16 MB   bf16 [NE][HID][DIM](dead after gemm1)
  //   part @ ~80.1M   16 MB   fp32 [NT][DIM]     (aliases xb+w1t head)
  char* ws = (char*)d_ws;
  float* wgt = (float*)(ws);
  short* w2t = (short*)(ws + 65536);
  short* hw  = (short*)(ws + 65536 + 16777216);
  short* xb  = (short*)(ws + 65536 + 16777216 + 67108864);
  short* w1t = (short*)(ws + 65536 + 16777216 + 67108864 + 8388608);
  float* part= (float*)(ws + 65536 + 16777216 + 67108864);   // aliases xb/w1t

  hipLaunchKernelGGL(router_cvt, dim3(NT / 4), dim3(256), 0, stream, x, Wr, br, wgt, xb);
  hipLaunchKernelGGL(transpose_all, dim3(2048 + 2048), dim3(256), 0, stream,
                     W1, w1t, W2, w2t);
  hipLaunchKernelGGL(gemm1_kernel, dim3(512), dim3(512), 0, stream,
                     xb, w1t, b1, wgt, hw);
  hipLaunchKernelGGL(gemm2_kernel, dim3(256), dim3(512), 0, stream,
                     hw, w2t, b2, wgt, out, part);
  hipLaunchKernelGGL(reduce_out, dim3(NT * DIM / 1024), dim3(256), 0, stream, out, part);
}